// Round 7
// baseline (152.866 us; speedup 1.0000x reference)
//
#include <hip/hip_runtime.h>
#include <math.h>

#define N_LAYERS 200
#define KSIZE 7
#define L_IN 1388
#define FC_IN 188
#define FC_OUT 91
#define NT 256        // 4 waves: quarter-splits of a 2-row (float2) payload
#define RMAX 7
#define NSTAGES 13    // 12 stages of 16 layers (margin 96) + 1 of 8 (margin 48)

typedef float2 f2;

constexpr int stage_lo(int s)  { return 16 * s; }
constexpr int stage_hi(int s)  { return (s < NSTAGES - 1) ? 16 * s + 16 : N_LAYERS; }
constexpr int len_after(int s) { return L_IN - 6 * stage_hi(s); }          // 1292..188
constexpr int stage_M(int s)   { return 6 * (stage_hi(s) - stage_lo(s)); } // 96 or 48
constexpr int stage_q(int s)   { return len_after(s) / 4; }
constexpr int stage_R(int s) {
    const int own3 = len_after(s) - 3 * stage_q(s);
    return (own3 + stage_M(s) + 63) / 64;   // 7,7,6,6,6,5,5,4,4,4,3,3,2
}

// One stage of layers [i0,i1), R float2 values/lane, shfl-pipelined halo.
//  - r[k] = positions wid*q + lane*R + k of current layer's input, 2 rows.
//  - h[t] = positions wid*q + lane*R + R + t, fetched the PREVIOUS layer.
//  - Ascending in-place update is safe (output k overwrites input k only).
//  - Garbage creeps left 6/layer from region end; margin M absorbs exactly
//    the stage's layers (exact-fit arithmetic as in rounds 5/6).
template<int R, bool RELU>
__device__ __forceinline__ void run_stage(f2 (&r)[RMAX], f2 (&h)[6],
                                          const float* __restrict__ cw,
                                          const float* __restrict__ cb,
                                          int i0, int i1)
{
    constexpr int S = (R < 6) ? R : 6;
    float w[KSIZE], b;
#pragma unroll
    for (int d = 0; d < KSIZE; ++d) w[d] = cw[i0 * KSIZE + d];
    b = cb[i0];

#pragma unroll 1
    for (int i = i0; i < i1; ++i) {
        // update k = 0..S-1 (consumes h when R < 12; both rows per FMA pair)
#pragma unroll
        for (int k = 0; k < S; ++k) {
            float ax = b, ay = b;
#pragma unroll
            for (int d = 0; d < KSIZE; ++d) {
                const int m = k + d;
                const f2 v = (m < R) ? r[m] : h[m - R];  // compile-time select
                ax = fmaf(w[d], v.x, ax);
                ay = fmaf(w[d], v.y, ay);
            }
            r[k].x = RELU ? fmaxf(ax, 0.0f) : ax;
            r[k].y = RELU ? fmaxf(ay, 0.0f) : ay;
        }

        // next layer's halo: just-updated r[..] of lanes +1..+3 (2 bperm/val)
        f2 hn[6];
#pragma unroll
        for (int t = 0; t < 6; ++t) {
            hn[t].x = __shfl_down(r[t % R].x, 1 + t / R);
            hn[t].y = __shfl_down(r[t % R].y, 1 + t / R);
        }

        // prefetch next layer's weights (uniform -> scalar loads)
        float w2[KSIZE], b2;
        const int ip = (i + 1 < i1) ? (i + 1) : i;
#pragma unroll
        for (int d = 0; d < KSIZE; ++d) w2[d] = cw[ip * KSIZE + d];
        b2 = cb[ip];

        // update k = S..R-1 (consumes h fetched one layer ago; empty if R<=6)
#pragma unroll
        for (int k = S; k < R; ++k) {
            float ax = b, ay = b;
#pragma unroll
            for (int d = 0; d < KSIZE; ++d) {
                const int m = k + d;
                const f2 v = (m < R) ? r[m] : h[m - R];
                ax = fmaf(w[d], v.x, ax);
                ay = fmaf(w[d], v.y, ay);
            }
            r[k].x = RELU ? fmaxf(ax, 0.0f) : ax;
            r[k].y = RELU ? fmaxf(ay, 0.0f) : ay;
        }

#pragma unroll
        for (int t = 0; t < 6; ++t) h[t] = hn[t];
#pragma unroll
        for (int d = 0; d < KSIZE; ++d) w[d] = w2[d];
        b = b2;
    }
}

// Cross-wave repack: write owned valid values at global row positions,
// barrier, read next stage's region + halo, barrier.
template<int Ro, int Rn>
__device__ __forceinline__ void repack(f2 (&r)[RMAX], f2 (&h)[6], f2* lbuf,
                                       int lane, int wid,
                                       int q_o, int len_o, int q_n)
{
    const int base_o = wid * q_o;
    const int bound  = (wid == 3) ? len_o : base_o + q_o;
#pragma unroll
    for (int k = 0; k < Ro; ++k) {
        const int g = base_o + lane * Ro + k;
        if (g < bound) lbuf[g] = r[k];
    }
    __syncthreads();
    const int base_n = wid * q_n;
#pragma unroll
    for (int k = 0; k < Rn; ++k) r[k] = lbuf[base_n + lane * Rn + k];
#pragma unroll
    for (int t = 0; t < 6; ++t) h[t] = lbuf[base_n + lane * Rn + Rn + t];
    __syncthreads();
}

template<int S>
struct Chain {
    __device__ static __forceinline__ void run(f2 (&r)[RMAX], f2 (&h)[6],
        const float* __restrict__ cw, const float* __restrict__ cb,
        f2* lbuf, int lane, int wid)
    {
        run_stage<stage_R(S), true>(r, h, cw, cb, stage_lo(S), stage_hi(S));
        repack<stage_R(S), stage_R(S + 1)>(r, h, lbuf, lane, wid,
                                           stage_q(S), len_after(S), stage_q(S + 1));
        Chain<S + 1>::run(r, h, cw, cb, lbuf, lane, wid);
    }
};

template<>
struct Chain<NSTAGES - 1> {
    __device__ static __forceinline__ void run(f2 (&r)[RMAX], f2 (&h)[6],
        const float* __restrict__ cw, const float* __restrict__ cb,
        f2* lbuf, int lane, int wid)
    {
        constexpr int R = stage_R(NSTAGES - 1);  // 2
        run_stage<R, true >(r, h, cw, cb, stage_lo(NSTAGES - 1), N_LAYERS - 1);
        run_stage<R, false>(r, h, cw, cb, N_LAYERS - 1, N_LAYERS);
        // final gather: owned values -> lbuf[0..188)
        constexpr int q1 = 188 / 4;  // 47
        const int base_o = wid * q1;
        const int bound  = (wid == 3) ? FC_IN : base_o + q1;
#pragma unroll
        for (int k = 0; k < R; ++k) {
            const int g = base_o + lane * R + k;
            if (g < bound) lbuf[g] = r[k];
        }
        __syncthreads();
    }
};

__global__ __launch_bounds__(NT) void conv_chain_kernel(
    const float* __restrict__ x,
    const float* __restrict__ conv_w,
    const float* __restrict__ conv_b,
    const float* __restrict__ fc_w,
    const float* __restrict__ fc_b,
    float* __restrict__ out)
{
    // max repack read index: 3*q(1) + 64*R(1) + 5 = 897+448+5 = 1350 -> 1360
    __shared__ __align__(16) f2 lbuf[1360];   // 10.9 KB

    const int tid  = threadIdx.x;
    const int lane = tid & 63;
    const int wid  = tid >> 6;
    const int rowA = 2 * blockIdx.x;
    const int rowB = rowA + 1;

    // Stage-0 region load from global for both rows (float2 payload).
    float2 r[RMAX], h[6];
    const float* xa = x + (size_t)rowA * L_IN;
    const float* xb = x + (size_t)rowB * L_IN;
    constexpr int R0 = stage_R(0);            // 7
    const int c0 = wid * stage_q(0);          // wid * 323
#pragma unroll
    for (int k = 0; k < R0; ++k) {
        const int p = c0 + lane * R0 + k;
        const bool ok = (p < L_IN);
        r[k].x = ok ? xa[p] : 0.0f;
        r[k].y = ok ? xb[p] : 0.0f;
    }
#pragma unroll
    for (int t = 0; t < 6; ++t) {
        const int p = c0 + lane * R0 + R0 + t;
        const bool ok = (p < L_IN);
        h[t].x = ok ? xa[p] : 0.0f;
        h[t].y = ok ? xb[p] : 0.0f;
    }

    Chain<0>::run(r, h, conv_w, conv_b, lbuf, lane, wid);

    // FC(188 -> 91) + sigmoid for both rows.
    if (tid < FC_OUT) {
        float accx = fc_b[tid], accy = accx;
        const float* wr = fc_w + tid * FC_IN;
#pragma unroll 4
        for (int j = 0; j < FC_IN; ++j) {
            const f2 hv = lbuf[j];
            const float wv = wr[j];
            accx = fmaf(wv, hv.x, accx);
            accy = fmaf(wv, hv.y, accy);
        }
        out[(size_t)rowA * FC_OUT + tid] = 1.0f / (1.0f + expf(-accx));
        out[(size_t)rowB * FC_OUT + tid] = 1.0f / (1.0f + expf(-accy));
    }
}

extern "C" void kernel_launch(void* const* d_in, const int* in_sizes, int n_in,
                              void* d_out, int out_size, void* d_ws, size_t ws_size,
                              hipStream_t stream) {
    const float* x      = (const float*)d_in[0];
    const float* conv_w = (const float*)d_in[1];
    const float* conv_b = (const float*)d_in[2];
    const float* fc_w   = (const float*)d_in[3];
    const float* fc_b   = (const float*)d_in[4];
    float* outp = (float*)d_out;

    const int batch = in_sizes[0] / L_IN;  // 1024 rows, 2 rows per block
    conv_chain_kernel<<<batch / 2, NT, 0, stream>>>(x, conv_w, conv_b, fc_w, fc_b, outp);
}

// Round 9
// 127.718 us; speedup vs baseline: 1.1969x; 1.1969x over previous
//
#include <hip/hip_runtime.h>
#include <math.h>

#define N_LAYERS 200
#define KSIZE 7
#define L_IN 1388
#define FC_IN 188
#define FC_OUT 91
#define NT 128        // 2 waves per row, independent between repacks
#define RMAX 12
#define NSTAGES 13    // 12 stages of 16 layers (margin 96) + 1 of 8 (margin 48)

// ---- Stage tables (2-wave split, margin = 6 * stage_layers) ----
constexpr int s_lo(int s)  { return 16 * s; }
constexpr int s_hi(int s)  { return (s < 12) ? 16 * s + 16 : N_LAYERS; }
constexpr int lin_(int s)  { return L_IN - 6 * s_lo(s); }   // input len of stage s
constexpr int lout_(int s) { return L_IN - 6 * s_hi(s); }   // valid len after stage s
constexpr int cut_(int s)  { return lout_(s) / 2; }         // wave0 owns [0,cut), wave1 [cut,lout)
constexpr int marg_(int s) { return 6 * (s_hi(s) - s_lo(s)); }
constexpr int s_R(int s) {
    const int a = cut_(s) + marg_(s);        // wave0 region size
    const int b = lin_(s) - cut_(s);         // wave1 region size
    const int m = (a > b) ? a : b;
    return (m + 63) / 64;                    // 12,11,11,10,9,8,8,7,6,5,5,4,3
}

// lane i <- lane i+1 (__shfl_down-by-1 direction = wave_shl:1 = ctrl 0x130;
// NOT 0x138/wave_shr, which pulls from lane i-1 — that was round 8's bug).
// Lane 63 gets 0 via bound_ctrl -> lands in the garbage-creep margin.
__device__ __forceinline__ float dpp_next(float v) {
    return __int_as_float(
        __builtin_amdgcn_mov_dpp(__float_as_int(v), 0x130, 0xf, 0xf, true));
}

// One stage of layers [i0,i1) with R values/lane.
//  - r[k] = position base + lane*R + k of the current layer's input.
//  - Halo (positions lane*R+R .. +5) fetched fresh each layer via DPP from
//    lane+1 (and lane+2 when R<6) BEFORE any update -> no latency, no state.
//  - Ascending in-place update is safe (output k overwrites input k only).
//  - Garbage creeps left 6/layer from region end; margin absorbs it exactly.
template<int R, bool RELU>
__device__ __forceinline__ void run_stage(float (&r)[RMAX],
                                          const float* __restrict__ cw,
                                          const float* __restrict__ cb,
                                          int i0, int i1)
{
    constexpr int T1N = (R < 6) ? R : 6;
    constexpr int T2N = (R < 6) ? (6 - R) : 0;

    float w[KSIZE], b;
#pragma unroll
    for (int d = 0; d < KSIZE; ++d) w[d] = cw[i0 * KSIZE + d];
    b = cb[i0];

#pragma unroll 1
    for (int i = i0; i < i1; ++i) {
        // halo via DPP (pre-update values of lane+1 / lane+2)
        float t1[T1N];
#pragma unroll
        for (int t = 0; t < T1N; ++t) t1[t] = dpp_next(r[t]);
        float t2[T2N ? T2N : 1];
        if constexpr (T2N > 0) {
#pragma unroll
            for (int u = 0; u < T2N; ++u) t2[u] = dpp_next(t1[u]);
        }

        // prefetch next layer's weights (uniform -> s_load), consumed next iter
        float w2[KSIZE], b2;
        const int ip = (i + 1 < i1) ? (i + 1) : i;
#pragma unroll
        for (int d = 0; d < KSIZE; ++d) w2[d] = cw[ip * KSIZE + d];
        b2 = cb[ip];

        // ascending in-place update
#pragma unroll
        for (int k = 0; k < R; ++k) {
            float acc = b;
#pragma unroll
            for (int d = 0; d < KSIZE; ++d) {
                const int m = k + d;  // compile-time select of source
                const float v = (m < R) ? r[m]
                              : ((m - R < T1N) ? t1[m - R] : t2[m - 2 * R]);
                acc = fmaf(w[d], v, acc);
            }
            r[k] = RELU ? fmaxf(acc, 0.0f) : acc;
        }

#pragma unroll
        for (int d = 0; d < KSIZE; ++d) w[d] = w2[d];
        b = b2;
    }
}

// Cross-wave repack after stage s: write owned valid values at global row
// positions, barrier, read next stage's region, barrier.
template<int Ro, int Rn>
__device__ __forceinline__ void repack(float (&r)[RMAX], float* lbuf,
                                       int lane, int wid,
                                       int cut_o, int lout_o, int cut_n)
{
    const int base_o = wid ? cut_o : 0;
    const int bound  = wid ? lout_o : cut_o;
#pragma unroll
    for (int k = 0; k < Ro; ++k) {
        const int g = base_o + lane * Ro + k;
        if (g < bound) lbuf[g] = r[k];
    }
    __syncthreads();
    const int base_n = wid ? cut_n : 0;
#pragma unroll
    for (int k = 0; k < Rn; ++k) r[k] = lbuf[base_n + lane * Rn + k];
    __syncthreads();
}

template<int S>
struct Chain {
    __device__ static __forceinline__ void run(float (&r)[RMAX],
        const float* __restrict__ cw, const float* __restrict__ cb,
        float* lbuf, int lane, int wid)
    {
        run_stage<s_R(S), true>(r, cw, cb, s_lo(S), s_hi(S));
        repack<s_R(S), s_R(S + 1)>(r, lbuf, lane, wid,
                                   cut_(S), lout_(S), cut_(S + 1));
        Chain<S + 1>::run(r, cw, cb, lbuf, lane, wid);
    }
};

template<>
struct Chain<NSTAGES - 1> {
    __device__ static __forceinline__ void run(float (&r)[RMAX],
        const float* __restrict__ cw, const float* __restrict__ cb,
        float* lbuf, int lane, int wid)
    {
        constexpr int R = s_R(NSTAGES - 1);  // 3
        run_stage<R, true >(r, cw, cb, s_lo(NSTAGES - 1), N_LAYERS - 1);
        run_stage<R, false>(r, cw, cb, N_LAYERS - 1, N_LAYERS);
        // final gather: wave0 owns [0,94), wave1 [94,188) -> lbuf[0..188)
        const int base_o = wid ? 94 : 0;
        const int bound  = wid ? FC_IN : 94;
#pragma unroll
        for (int k = 0; k < R; ++k) {
            const int g = base_o + lane * R + k;
            if (g < bound) lbuf[g] = r[k];
        }
        __syncthreads();
    }
};

__global__ __launch_bounds__(NT) void conv_chain_kernel(
    const float* __restrict__ x,
    const float* __restrict__ conv_w,
    const float* __restrict__ conv_b,
    const float* __restrict__ fc_w,
    const float* __restrict__ fc_b,
    float* __restrict__ out)
{
    // max repack read index: cut(1) + 64*R(1) = 598 + 704 = 1302 -> 1312
    __shared__ __align__(16) float lbuf[1312];

    const int row  = blockIdx.x;
    const int tid  = threadIdx.x;
    const int lane = tid & 63;
    const int wid  = tid >> 6;

    // Stage-0 region load from global: wave0 base 0, wave1 base cut(0)=646.
    float r[RMAX];
    const float* xr = x + (size_t)row * L_IN;
    constexpr int R0 = s_R(0);               // 12
    const int c0 = wid ? cut_(0) : 0;
#pragma unroll
    for (int k = 0; k < R0; ++k) {
        const int p = c0 + lane * R0 + k;
        r[k] = (p < L_IN) ? xr[p] : 0.0f;
    }

    Chain<0>::run(r, conv_w, conv_b, lbuf, lane, wid);

    // FC(188 -> 91) + sigmoid.
    if (tid < FC_OUT) {
        float acc = fc_b[tid];
        const float4* wp = (const float4*)(fc_w + tid * FC_IN);  // 752B rows: 16B-aligned
        const float4* hp = (const float4*)lbuf;
#pragma unroll 4
        for (int q = 0; q < FC_IN / 4; ++q) {
            const float4 hv = hp[q];
            const float4 wv = wp[q];
            acc = fmaf(wv.x, hv.x, acc);
            acc = fmaf(wv.y, hv.y, acc);
            acc = fmaf(wv.z, hv.z, acc);
            acc = fmaf(wv.w, hv.w, acc);
        }
        out[(size_t)row * FC_OUT + tid] = 1.0f / (1.0f + expf(-acc));
    }
}

extern "C" void kernel_launch(void* const* d_in, const int* in_sizes, int n_in,
                              void* d_out, int out_size, void* d_ws, size_t ws_size,
                              hipStream_t stream) {
    const float* x      = (const float*)d_in[0];
    const float* conv_w = (const float*)d_in[1];
    const float* conv_b = (const float*)d_in[2];
    const float* fc_w   = (const float*)d_in[3];
    const float* fc_b   = (const float*)d_in[4];
    float* outp = (float*)d_out;

    const int batch = in_sizes[0] / L_IN;  // 1024 rows, 2 independent waves each
    conv_chain_kernel<<<batch, NT, 0, stream>>>(x, conv_w, conv_b, fc_w, fc_b, outp);
}

// Round 10
// 119.994 us; speedup vs baseline: 1.2739x; 1.0644x over previous
//
#include <hip/hip_runtime.h>
#include <math.h>

#define N_LAYERS 200
#define KSIZE 7
#define L_IN 1388
#define FC_IN 188
#define FC_OUT 91
#define NT 128        // 2 waves per row, independent between repacks
#define RMAX 12
#define NSTAGES 13    // 12 stages of 16 layers (margin 96) + 1 of 8 (margin 48)

// ---- Stage tables (2-wave split, margin = 6 * stage_layers) ----
constexpr int s_lo(int s)  { return 16 * s; }
constexpr int s_hi(int s)  { return (s < 12) ? 16 * s + 16 : N_LAYERS; }
constexpr int lin_(int s)  { return L_IN - 6 * s_lo(s); }   // input len of stage s
constexpr int lout_(int s) { return L_IN - 6 * s_hi(s); }   // valid len after stage s
constexpr int cut_(int s)  { return lout_(s) / 2; }         // wave0 owns [0,cut), wave1 [cut,lout)
constexpr int marg_(int s) { return 6 * (s_hi(s) - s_lo(s)); }
constexpr int s_R(int s) {
    const int a = cut_(s) + marg_(s);        // wave0 region size
    const int b = lin_(s) - cut_(s);         // wave1 region size
    const int m = (a > b) ? a : b;
    return (m + 63) / 64;                    // 12,11,11,10,9,8,8,7,6,5,5,4,3
}

// lane i <- lane i+1 (wave_shl:1 = ctrl 0x130). Lane 63 gets 0 via
// bound_ctrl -> lands in the garbage-creep margin.
__device__ __forceinline__ float dpp_next(float v) {
    return __int_as_float(
        __builtin_amdgcn_mov_dpp(__float_as_int(v), 0x130, 0xf, 0xf, true));
}

// 4-layer weight group: 28 taps + 4 biases, loaded as 8 float4s.
struct WG { float w[28]; float b[4]; };

__device__ __forceinline__ void load_wg(WG& wg, const float4* __restrict__ cw4,
                                        const float4* __restrict__ cb4, int g) {
#pragma unroll
    for (int t = 0; t < 7; ++t) {
        const float4 v = cw4[g * 7 + t];
        wg.w[4 * t + 0] = v.x; wg.w[4 * t + 1] = v.y;
        wg.w[4 * t + 2] = v.z; wg.w[4 * t + 3] = v.w;
    }
    const float4 bv = cb4[g];
    wg.b[0] = bv.x; wg.b[1] = bv.y; wg.b[2] = bv.z; wg.b[3] = bv.w;
}

// 4 layers with R values/lane. NR3: skip ReLU on the group's last layer
// (only group 49 / layer 199). Invariants as round 9: DPP halo fetched
// pre-update each layer; ascending in-place update; garbage creeps left
// 6/layer into the stage margin.
template<int R, bool NR3>
__device__ __forceinline__ void run4(float (&r)[RMAX], const WG& wg) {
    constexpr int T1N = (R < 6) ? R : 6;
    constexpr int T2N = (R < 6) ? (6 - R) : 0;
#pragma unroll
    for (int j = 0; j < 4; ++j) {
        float t1[T1N];
#pragma unroll
        for (int t = 0; t < T1N; ++t) t1[t] = dpp_next(r[t]);
        float t2[T2N ? T2N : 1];
        if constexpr (T2N > 0) {
#pragma unroll
            for (int u = 0; u < T2N; ++u) t2[u] = dpp_next(t1[u]);
        }
        const bool relu = !(NR3 && j == 3);
#pragma unroll
        for (int k = 0; k < R; ++k) {
            float acc = wg.b[j];
#pragma unroll
            for (int d = 0; d < KSIZE; ++d) {
                const int m = k + d;  // compile-time select of source
                const float v = (m < R) ? r[m]
                              : ((m - R < T1N) ? t1[m - R] : t2[m - 2 * R]);
                acc = fmaf(wg.w[j * 7 + d], v, acc);
            }
            r[k] = relu ? fmaxf(acc, 0.0f) : acc;
        }
    }
}

// One stage = groups [g0,g1), processed in ping-pong pairs. Invariant at
// entry: A holds group g0's weights. While a group computes, the next
// group's 8 float4 loads are in flight (~4x body cycles of cover) -> weight
// latency fully hidden; no copy movs (loads land directly in A/B).
template<int R, bool FINAL>
__device__ __forceinline__ void run_stage_g(float (&r)[RMAX], WG& A,
        const float4* __restrict__ cw4, const float4* __restrict__ cb4,
        int g0, int g1) {
#pragma unroll 1
    for (int g = g0; g < g1; g += 2) {
        WG B;
        load_wg(B, cw4, cb4, (g + 1 < 50) ? g + 1 : 49);
        run4<R, false>(r, A);
        load_wg(A, cw4, cb4, (g + 2 < 50) ? g + 2 : 49);
        run4<R, FINAL>(r, B);
    }
}

// Cross-wave repack after stage s: write owned valid values at global row
// positions, barrier, read next stage's region, barrier.
template<int Ro, int Rn>
__device__ __forceinline__ void repack(float (&r)[RMAX], float* lbuf,
                                       int lane, int wid,
                                       int cut_o, int lout_o, int cut_n)
{
    const int base_o = wid ? cut_o : 0;
    const int bound  = wid ? lout_o : cut_o;
#pragma unroll
    for (int k = 0; k < Ro; ++k) {
        const int g = base_o + lane * Ro + k;
        if (g < bound) lbuf[g] = r[k];
    }
    __syncthreads();
    const int base_n = wid ? cut_n : 0;
#pragma unroll
    for (int k = 0; k < Rn; ++k) r[k] = lbuf[base_n + lane * Rn + k];
    __syncthreads();
}

template<int S>
struct Chain {
    __device__ static __forceinline__ void run(float (&r)[RMAX], WG& A,
        const float4* __restrict__ cw4, const float4* __restrict__ cb4,
        float* lbuf, int lane, int wid)
    {
        run_stage_g<s_R(S), false>(r, A, cw4, cb4, 4 * S, 4 * S + 4);
        repack<s_R(S), s_R(S + 1)>(r, lbuf, lane, wid,
                                   cut_(S), lout_(S), cut_(S + 1));
        Chain<S + 1>::run(r, A, cw4, cb4, lbuf, lane, wid);
    }
};

template<>
struct Chain<NSTAGES - 1> {
    __device__ static __forceinline__ void run(float (&r)[RMAX], WG& A,
        const float4* __restrict__ cw4, const float4* __restrict__ cb4,
        float* lbuf, int lane, int wid)
    {
        constexpr int R = s_R(NSTAGES - 1);  // 3; groups 48,49 (layer 199 no ReLU)
        run_stage_g<R, true>(r, A, cw4, cb4, 48, 50);
        // final gather: wave0 owns [0,94), wave1 [94,188) -> lbuf[0..188)
        const int base_o = wid ? 94 : 0;
        const int bound  = wid ? FC_IN : 94;
#pragma unroll
        for (int k = 0; k < R; ++k) {
            const int g = base_o + lane * R + k;
            if (g < bound) lbuf[g] = r[k];
        }
        __syncthreads();
    }
};

__global__ __launch_bounds__(NT) void conv_chain_kernel(
    const float* __restrict__ x,
    const float* __restrict__ conv_w,
    const float* __restrict__ conv_b,
    const float* __restrict__ fc_w,
    const float* __restrict__ fc_b,
    float* __restrict__ out)
{
    // max repack read index: cut(1) + 64*R(1) = 598 + 704 = 1302 -> 1312
    __shared__ __align__(16) float lbuf[1312];

    const int row  = blockIdx.x;
    const int tid  = threadIdx.x;
    const int lane = tid & 63;
    const int wid  = tid >> 6;

    const float4* cw4 = (const float4*)conv_w;  // 1400 floats = 350 float4
    const float4* cb4 = (const float4*)conv_b;  // 200 floats = 50 float4

    // Preload group 0's weights (rolling ping-pong starts here).
    WG A;
    load_wg(A, cw4, cb4, 0);

    // Stage-0 region load from global: wave0 base 0, wave1 base cut(0)=646.
    float r[RMAX];
    const float* xr = x + (size_t)row * L_IN;
    constexpr int R0 = s_R(0);               // 12
    const int c0 = wid ? cut_(0) : 0;
#pragma unroll
    for (int k = 0; k < R0; ++k) {
        const int p = c0 + lane * R0 + k;
        r[k] = (p < L_IN) ? xr[p] : 0.0f;
    }

    Chain<0>::run(r, A, cw4, cb4, lbuf, lane, wid);

    // FC(188 -> 91) + sigmoid.
    if (tid < FC_OUT) {
        float acc = fc_b[tid];
        const float4* wp = (const float4*)(fc_w + tid * FC_IN);  // 752B rows: 16B-aligned
        const float4* hp = (const float4*)lbuf;
#pragma unroll 4
        for (int q = 0; q < FC_IN / 4; ++q) {
            const float4 hv = hp[q];
            const float4 wv = wp[q];
            acc = fmaf(wv.x, hv.x, acc);
            acc = fmaf(wv.y, hv.y, acc);
            acc = fmaf(wv.z, hv.z, acc);
            acc = fmaf(wv.w, hv.w, acc);
        }
        out[(size_t)row * FC_OUT + tid] = 1.0f / (1.0f + expf(-acc));
    }
}

extern "C" void kernel_launch(void* const* d_in, const int* in_sizes, int n_in,
                              void* d_out, int out_size, void* d_ws, size_t ws_size,
                              hipStream_t stream) {
    const float* x      = (const float*)d_in[0];
    const float* conv_w = (const float*)d_in[1];
    const float* conv_b = (const float*)d_in[2];
    const float* fc_w   = (const float*)d_in[3];
    const float* fc_b   = (const float*)d_in[4];
    float* outp = (float*)d_out;

    const int batch = in_sizes[0] / L_IN;  // 1024 rows, 2 independent waves each
    conv_chain_kernel<<<batch, NT, 0, stream>>>(x, conv_w, conv_b, fc_w, fc_b, outp);
}

// Round 11
// 119.621 us; speedup vs baseline: 1.2779x; 1.0031x over previous
//
#include <hip/hip_runtime.h>
#include <math.h>

#define N_LAYERS 200
#define KSIZE 7
#define L_IN 1388
#define FC_IN 188
#define FC_OUT 91
#define NT 128        // 2 waves per row, independent between repacks
#define RMAX 12
#define NSTAGES 13    // 12 stages of 16 layers (margin 96) + 1 of 8 (margin 48)

// ---- Stage tables (2-wave split, margin = 6 * stage_layers) ----
constexpr int s_lo(int s)  { return 16 * s; }
constexpr int s_hi(int s)  { return (s < 12) ? 16 * s + 16 : N_LAYERS; }
constexpr int lin_(int s)  { return L_IN - 6 * s_lo(s); }   // input len of stage s
constexpr int lout_(int s) { return L_IN - 6 * s_hi(s); }   // valid len after stage s
constexpr int cut_(int s)  { return lout_(s) / 2; }         // wave0 owns [0,cut), wave1 [cut,lout)
constexpr int marg_(int s) { return 6 * (s_hi(s) - s_lo(s)); }
constexpr int s_R(int s) {
    const int a = cut_(s) + marg_(s);        // wave0 region size
    const int b = lin_(s) - cut_(s);         // wave1 region size
    const int m = (a > b) ? a : b;
    return (m + 63) / 64;                    // 12,11,11,10,9,8,8,7,6,5,5,4,3
}

// lane i <- lane i+1 (wave_shl:1 = ctrl 0x130). Lane 63 gets 0 via
// bound_ctrl -> lands in the garbage-creep margin.
__device__ __forceinline__ float dpp_next(float v) {
    return __int_as_float(
        __builtin_amdgcn_mov_dpp(__float_as_int(v), 0x130, 0xf, 0xf, true));
}

// 4-layer weight group: 28 taps + 4 biases, loaded as 8 float4s (s_loads).
struct WG { float w[28]; float b[4]; };

__device__ __forceinline__ void load_wg(WG& wg, const float4* __restrict__ cw4,
                                        const float4* __restrict__ cb4, int g) {
#pragma unroll
    for (int t = 0; t < 7; ++t) {
        const float4 v = cw4[g * 7 + t];
        wg.w[4 * t + 0] = v.x; wg.w[4 * t + 1] = v.y;
        wg.w[4 * t + 2] = v.z; wg.w[4 * t + 3] = v.w;
    }
    const float4 bv = cb4[g];
    wg.b[0] = bv.x; wg.b[1] = bv.y; wg.b[2] = bv.z; wg.b[3] = bv.w;
}

// 4 layers with R values/lane, D-MAJOR accumulation:
//  - t1/t2 = halo (pre-update values of lane+1 / lane+2) via DPP.
//  - acc[k] initialized from bias at d=0, then taps d=1..6 applied k-inner:
//    consecutive FMAs hit DIFFERENT accumulators -> R-way ILP by
//    construction, immune to min-pressure scheduling (round-10 stall).
//  - r[] read-only during the layer, overwritten at the end -> no in-place
//    hazard. Garbage creeps left 6/layer into the stage margin as before.
template<int R, bool NR3>
__device__ __forceinline__ void run4(float (&r)[RMAX], const WG& wg) {
    constexpr int T1N = (R < 6) ? R : 6;
    constexpr int T2N = (R < 6) ? (6 - R) : 0;
#pragma unroll
    for (int j = 0; j < 4; ++j) {
        float t1[T1N];
#pragma unroll
        for (int t = 0; t < T1N; ++t) t1[t] = dpp_next(r[t]);
        float t2[T2N ? T2N : 1];
        if constexpr (T2N > 0) {
#pragma unroll
            for (int u = 0; u < T2N; ++u) t2[u] = dpp_next(t1[u]);
        }

        float acc[R];
#pragma unroll
        for (int d = 0; d < KSIZE; ++d) {
            const float wd = wg.w[j * 7 + d];
#pragma unroll
            for (int k = 0; k < R; ++k) {
                const int m = k + d;  // compile-time select of source
                const float v = (m < R) ? r[m]
                              : ((m - R < T1N) ? t1[m - R] : t2[m - 2 * R]);
                acc[k] = (d == 0) ? fmaf(wd, v, wg.b[j]) : fmaf(wd, v, acc[k]);
            }
        }

        const bool relu = !(NR3 && j == 3);
#pragma unroll
        for (int k = 0; k < R; ++k)
            r[k] = relu ? fmaxf(acc[k], 0.0f) : acc[k];
    }
}

// One stage = groups [g0,g1), ping-pong weight double-buffer: while a group
// computes, the next group's 8 s_load_x4 are in flight.
template<int R, bool FINAL>
__device__ __forceinline__ void run_stage_g(float (&r)[RMAX], WG& A,
        const float4* __restrict__ cw4, const float4* __restrict__ cb4,
        int g0, int g1) {
#pragma unroll 1
    for (int g = g0; g < g1; g += 2) {
        WG B;
        load_wg(B, cw4, cb4, (g + 1 < 50) ? g + 1 : 49);
        run4<R, false>(r, A);
        load_wg(A, cw4, cb4, (g + 2 < 50) ? g + 2 : 49);
        run4<R, FINAL>(r, B);
    }
}

// Cross-wave repack after stage s: write owned valid values at global row
// positions, barrier, read next stage's region, barrier.
template<int Ro, int Rn>
__device__ __forceinline__ void repack(float (&r)[RMAX], float* lbuf,
                                       int lane, int wid,
                                       int cut_o, int lout_o, int cut_n)
{
    const int base_o = wid ? cut_o : 0;
    const int bound  = wid ? lout_o : cut_o;
#pragma unroll
    for (int k = 0; k < Ro; ++k) {
        const int g = base_o + lane * Ro + k;
        if (g < bound) lbuf[g] = r[k];
    }
    __syncthreads();
    const int base_n = wid ? cut_n : 0;
#pragma unroll
    for (int k = 0; k < Rn; ++k) r[k] = lbuf[base_n + lane * Rn + k];
    __syncthreads();
}

template<int S>
struct Chain {
    __device__ static __forceinline__ void run(float (&r)[RMAX], WG& A,
        const float4* __restrict__ cw4, const float4* __restrict__ cb4,
        float* lbuf, int lane, int wid)
    {
        run_stage_g<s_R(S), false>(r, A, cw4, cb4, 4 * S, 4 * S + 4);
        repack<s_R(S), s_R(S + 1)>(r, lbuf, lane, wid,
                                   cut_(S), lout_(S), cut_(S + 1));
        Chain<S + 1>::run(r, A, cw4, cb4, lbuf, lane, wid);
    }
};

template<>
struct Chain<NSTAGES - 1> {
    __device__ static __forceinline__ void run(float (&r)[RMAX], WG& A,
        const float4* __restrict__ cw4, const float4* __restrict__ cb4,
        float* lbuf, int lane, int wid)
    {
        constexpr int R = s_R(NSTAGES - 1);  // 3; groups 48,49 (layer 199 no ReLU)
        run_stage_g<R, true>(r, A, cw4, cb4, 48, 50);
        // final gather: wave0 owns [0,94), wave1 [94,188) -> lbuf[0..188)
        const int base_o = wid ? 94 : 0;
        const int bound  = wid ? FC_IN : 94;
#pragma unroll
        for (int k = 0; k < R; ++k) {
            const int g = base_o + lane * R + k;
            if (g < bound) lbuf[g] = r[k];
        }
        __syncthreads();
    }
};

__global__ __launch_bounds__(NT, 2) void conv_chain_kernel(
    const float* __restrict__ x,
    const float* __restrict__ conv_w,
    const float* __restrict__ conv_b,
    const float* __restrict__ fc_w,
    const float* __restrict__ fc_b,
    float* __restrict__ out)
{
    // max repack read index: cut(1) + 64*R(1) = 598 + 704 = 1302 -> 1312
    __shared__ __align__(16) float lbuf[1312];

    const int row  = blockIdx.x;
    const int tid  = threadIdx.x;
    const int lane = tid & 63;
    const int wid  = tid >> 6;

    const float4* cw4 = (const float4*)conv_w;  // 1400 floats = 350 float4
    const float4* cb4 = (const float4*)conv_b;  // 200 floats = 50 float4

    // Preload group 0's weights (rolling ping-pong starts here).
    WG A;
    load_wg(A, cw4, cb4, 0);

    // Stage-0 region load from global: wave0 base 0, wave1 base cut(0)=646.
    float r[RMAX];
    const float* xr = x + (size_t)row * L_IN;
    constexpr int R0 = s_R(0);               // 12
    const int c0 = wid ? cut_(0) : 0;
#pragma unroll
    for (int k = 0; k < R0; ++k) {
        const int p = c0 + lane * R0 + k;
        r[k] = (p < L_IN) ? xr[p] : 0.0f;
    }

    Chain<0>::run(r, A, cw4, cb4, lbuf, lane, wid);

    // FC(188 -> 91) + sigmoid.
    if (tid < FC_OUT) {
        float acc = fc_b[tid];
        const float4* wp = (const float4*)(fc_w + tid * FC_IN);  // 752B rows: 16B-aligned
        const float4* hp = (const float4*)lbuf;
#pragma unroll 4
        for (int q = 0; q < FC_IN / 4; ++q) {
            const float4 hv = hp[q];
            const float4 wv = wp[q];
            acc = fmaf(wv.x, hv.x, acc);
            acc = fmaf(wv.y, hv.y, acc);
            acc = fmaf(wv.z, hv.z, acc);
            acc = fmaf(wv.w, hv.w, acc);
        }
        out[(size_t)row * FC_OUT + tid] = 1.0f / (1.0f + expf(-acc));
    }
}

extern "C" void kernel_launch(void* const* d_in, const int* in_sizes, int n_in,
                              void* d_out, int out_size, void* d_ws, size_t ws_size,
                              hipStream_t stream) {
    const float* x      = (const float*)d_in[0];
    const float* conv_w = (const float*)d_in[1];
    const float* conv_b = (const float*)d_in[2];
    const float* fc_w   = (const float*)d_in[3];
    const float* fc_b   = (const float*)d_in[4];
    float* outp = (float*)d_out;

    const int batch = in_sizes[0] / L_IN;  // 1024 rows, 2 independent waves each
    conv_chain_kernel<<<batch, NT, 0, stream>>>(x, conv_w, conv_b, fc_w, fc_b, outp);
}

// Round 12
// 114.985 us; speedup vs baseline: 1.3294x; 1.0403x over previous
//
#include <hip/hip_runtime.h>
#include <math.h>

#define N_LAYERS 200
#define KSIZE 7
#define L_IN 1388
#define FC_IN 188
#define FC_OUT 91
#define NT 128        // 2 waves per row, independent between repacks
#define NSTAGES 13    // 12 stages of 16 layers (margin 96) + 1 of 8 (margin 48)

typedef float v2f __attribute__((ext_vector_type(2)));

// ---- Stage tables (2-wave split, margin = 6 * stage_layers) ----
constexpr int s_lo(int s)  { return 16 * s; }
constexpr int s_hi(int s)  { return (s < 12) ? 16 * s + 16 : N_LAYERS; }
constexpr int lin_(int s)  { return L_IN - 6 * s_lo(s); }
constexpr int lout_(int s) { return L_IN - 6 * s_hi(s); }
constexpr int cut_(int s)  { return lout_(s) / 2; }   // all cuts even
constexpr int marg_(int s) { return 6 * (s_hi(s) - s_lo(s)); }
constexpr int s_R(int s) {
    const int a = cut_(s) + marg_(s);
    const int b = lin_(s) - cut_(s);
    const int m = (a > b) ? a : b;
    return (m + 63) / 64;
}
// Even-rounded R for pair storage: 12,12,12,10,10,8,8,8,6,6,6,4,4
constexpr int s_Re(int s) { return (s_R(s) + 1) & ~1; }

// lane i <- lane i+1 (wave_shl:1 = ctrl 0x130). Lane 63 gets 0 via
// bound_ctrl -> lands in the garbage-creep margin.
__device__ __forceinline__ float dpp_next(float v) {
    return __int_as_float(
        __builtin_amdgcn_mov_dpp(__float_as_int(v), 0x130, 0xf, 0xf, true));
}
__device__ __forceinline__ v2f dpp_next2(v2f v) {
    v2f o; o.x = dpp_next(v.x); o.y = dpp_next(v.y); return o;
}

__device__ __forceinline__ v2f pk_fma(v2f a, v2f b, v2f c) {
    return __builtin_elementwise_fma(a, b, c);   // -> v_pk_fma_f32
}
__device__ __forceinline__ v2f pk_max0(v2f a) {
    return __builtin_elementwise_max(a, (v2f)(0.0f));  // -> v_pk_max_f32
}

// 4-layer weight group, pre-splatted pairs {w,w} read from LDS.
struct WG { v2f w2[28]; v2f b2[4]; };

__device__ __forceinline__ void load_wg(WG& wg, const v2f* wbuf2,
                                        const v2f* bbuf2, int g) {
#pragma unroll
    for (int t = 0; t < 28; ++t) wg.w2[t] = wbuf2[g * 28 + t];
#pragma unroll
    for (int j = 0; j < 4; ++j) wg.b2[j] = bbuf2[g * 4 + j];
}

// 4 layers, R values/lane stored as P=R/2 position-pairs (both pk halves are
// adjacent POSITIONS of the same row).
//  - halo pairs h[0..2] = positions R..R+5 (lane+1, +2 when P<3) via DPP.
//  - even taps d: aligned pairs E(m) = r2[m] / h[m-P].
//  - odd taps d: misaligned pairs M[j] = {E(j).y, E(j+1).x}, prebuilt
//    pre-update (all reads are pre-update inputs).
//  - writing r2[j] ascending is safe: later j' reads only pairs >= j'.
//  - garbage creeps left 6/layer into the stage margin (as rounds 9-11).
template<int R, bool NR3>
__device__ __forceinline__ void run4(v2f (&r2)[6], const WG& wg) {
    constexpr int P = R / 2;
#pragma unroll
    for (int jj = 0; jj < 4; ++jj) {
        v2f h[3];
        {
            constexpr int L1 = (P < 3) ? P : 3;
            v2f l1[L1];
#pragma unroll
            for (int t = 0; t < L1; ++t) l1[t] = dpp_next2(r2[t]);
#pragma unroll
            for (int t = 0; t < L1; ++t) h[t] = l1[t];
            if constexpr (P == 2) h[2] = dpp_next2(l1[0]);  // lane+2 pair0
        }
        v2f M[P + 2];
#pragma unroll
        for (int j = 0; j < P + 2; ++j) {
            const v2f a = (j < P) ? r2[j] : h[j - P];
            const v2f b = (j + 1 < P) ? r2[j + 1] : h[j + 1 - P];
            v2f m; m.x = a.y; m.y = b.x;
            M[j] = m;
        }
        const bool relu = !(NR3 && jj == 3);
#pragma unroll
        for (int j = 0; j < P; ++j) {
            v2f acc = wg.b2[jj];
#pragma unroll
            for (int d = 0; d < KSIZE; ++d) {
                v2f src;
                if (d % 2 == 0) {
                    const int m = j + d / 2;           // compile-time select
                    src = (m < P) ? r2[m] : h[m - P];
                } else {
                    src = M[j + (d - 1) / 2];
                }
                acc = pk_fma(wg.w2[jj * 7 + d], src, acc);
            }
            r2[j] = relu ? pk_max0(acc) : acc;
        }
    }
}

// Stage = groups [g0,g1), ping-pong weight double-buffer (LDS -> regs).
template<int R, bool FINAL>
__device__ __forceinline__ void run_stage_g(v2f (&r2)[6], WG& A,
        const v2f* wbuf2, const v2f* bbuf2, int g0, int g1) {
#pragma unroll 1
    for (int g = g0; g < g1; g += 2) {
        WG B;
        load_wg(B, wbuf2, bbuf2, (g + 1 < 50) ? g + 1 : 49);
        run4<R, false>(r2, A);
        load_wg(A, wbuf2, bbuf2, (g + 2 < 50) ? g + 2 : 49);
        run4<R, FINAL>(r2, B);
    }
}

// Cross-wave repack (pair-indexed; all cuts/bounds are even).
template<int Ro, int Rn>
__device__ __forceinline__ void repack(v2f (&r2)[6], v2f* lbuf2,
                                       int lane, int wid,
                                       int cut_o, int lout_o, int cut_n)
{
    const int base2  = (wid ? cut_o : 0) / 2;
    const int bound2 = (wid ? lout_o : cut_o) / 2;
#pragma unroll
    for (int j = 0; j < Ro / 2; ++j) {
        const int pg = base2 + lane * (Ro / 2) + j;
        if (pg < bound2) lbuf2[pg] = r2[j];
    }
    __syncthreads();
    const int nb2 = (wid ? cut_n : 0) / 2;
#pragma unroll
    for (int j = 0; j < Rn / 2; ++j) r2[j] = lbuf2[nb2 + lane * (Rn / 2) + j];
    __syncthreads();
}

template<int S>
struct Chain {
    __device__ static __forceinline__ void run(v2f (&r2)[6], WG& A,
        const v2f* wbuf2, const v2f* bbuf2, v2f* lbuf2, int lane, int wid)
    {
        run_stage_g<s_Re(S), false>(r2, A, wbuf2, bbuf2, 4 * S, 4 * S + 4);
        repack<s_Re(S), s_Re(S + 1)>(r2, lbuf2, lane, wid,
                                     cut_(S), lout_(S), cut_(S + 1));
        Chain<S + 1>::run(r2, A, wbuf2, bbuf2, lbuf2, lane, wid);
    }
};

template<>
struct Chain<NSTAGES - 1> {
    __device__ static __forceinline__ void run(v2f (&r2)[6], WG& A,
        const v2f* wbuf2, const v2f* bbuf2, v2f* lbuf2, int lane, int wid)
    {
        constexpr int R = s_Re(NSTAGES - 1);  // 4; groups 48,49 (layer 199 no ReLU)
        run_stage_g<R, true>(r2, A, wbuf2, bbuf2, 48, 50);
        // final gather: wave0 owns pairs [0,47), wave1 [47,94) -> lbuf2[0..94)
        const int base2  = wid ? 47 : 0;
        const int bound2 = wid ? 94 : 47;
#pragma unroll
        for (int j = 0; j < R / 2; ++j) {
            const int pg = base2 + lane * (R / 2) + j;
            if (pg < bound2) lbuf2[pg] = r2[j];
        }
        __syncthreads();
    }
};

__global__ __launch_bounds__(NT, 2) void conv_chain_kernel(
    const float* __restrict__ x,
    const float* __restrict__ conv_w,
    const float* __restrict__ conv_b,
    const float* __restrict__ fc_w,
    const float* __restrict__ fc_b,
    float* __restrict__ out)
{
    // lbuf2: max read pair index 598/2 + 63*6 + 5 = 682 -> 688 (5.5 KB)
    __shared__ __align__(16) v2f lbuf2[688];
    __shared__ __align__(16) v2f wbuf2[N_LAYERS * KSIZE];  // splatted {w,w}, 11.2 KB
    __shared__ __align__(16) v2f bbuf2[N_LAYERS];          // splatted {b,b}, 1.6 KB

    const int row  = blockIdx.x;
    const int tid  = threadIdx.x;
    const int lane = tid & 63;
    const int wid  = tid >> 6;

    // Pre-splat weights into LDS (one-time, coalesced-ish).
    for (int i = tid; i < N_LAYERS * KSIZE; i += NT) {
        const float v = conv_w[i];
        v2f p; p.x = v; p.y = v; wbuf2[i] = p;
    }
    for (int i = tid; i < N_LAYERS; i += NT) {
        const float v = conv_b[i];
        v2f p; p.x = v; p.y = v; bbuf2[i] = p;
    }

    // Stage-0 region load (pairs; even offsets -> 8B-aligned v2f loads).
    v2f r2[6];
    const float* xr = x + (size_t)row * L_IN;
    const int c0 = wid ? cut_(0) : 0;   // 0 or 646
#pragma unroll
    for (int j = 0; j < 6; ++j) {
        const int p = c0 + lane * 12 + 2 * j;
        v2f v;
        if (p + 1 < L_IN)      v = *(const v2f*)(xr + p);
        else if (p < L_IN)     { v.x = xr[p]; v.y = 0.0f; }
        else                   { v.x = 0.0f;  v.y = 0.0f; }
        r2[j] = v;
    }
    __syncthreads();  // splat visible before first weight read

    WG A;
    load_wg(A, wbuf2, bbuf2, 0);

    Chain<0>::run(r2, A, wbuf2, bbuf2, lbuf2, lane, wid);

    // FC(188 -> 91) + sigmoid (pairs are contiguous positions).
    if (tid < FC_OUT) {
        float acc = fc_b[tid];
        const float4* wp = (const float4*)(fc_w + tid * FC_IN);
        const float4* hp = (const float4*)lbuf2;
#pragma unroll 4
        for (int q = 0; q < FC_IN / 4; ++q) {
            const float4 hv = hp[q];
            const float4 wv = wp[q];
            acc = fmaf(wv.x, hv.x, acc);
            acc = fmaf(wv.y, hv.y, acc);
            acc = fmaf(wv.z, hv.z, acc);
            acc = fmaf(wv.w, hv.w, acc);
        }
        out[(size_t)row * FC_OUT + tid] = 1.0f / (1.0f + expf(-acc));
    }
}

extern "C" void kernel_launch(void* const* d_in, const int* in_sizes, int n_in,
                              void* d_out, int out_size, void* d_ws, size_t ws_size,
                              hipStream_t stream) {
    const float* x      = (const float*)d_in[0];
    const float* conv_w = (const float*)d_in[1];
    const float* conv_b = (const float*)d_in[2];
    const float* fc_w   = (const float*)d_in[3];
    const float* fc_b   = (const float*)d_in[4];
    float* outp = (float*)d_out;

    const int batch = in_sizes[0] / L_IN;  // 1024 rows, 2 independent waves each
    conv_chain_kernel<<<batch, NT, 0, stream>>>(x, conv_w, conv_b, fc_w, fc_b, outp);
}